// Round 11
// baseline (377.516 us; speedup 1.0000x reference)
//
#include <hip/hip_runtime.h>

// SparseMaxPool — R10: INSTRUMENTED PROBE (not a perf attempt).
// R4/R6/R7/R9 (four different structures, occupancy 10-24 waves/CU, nt,
// pipelining) all ~95 us kernel time (~2.9 TB/s) vs 43 us @ fill-rate floor.
// Our dispatch never appears in the rocprof top-5 (fills ~167 us dominate),
// so we have NO counters for it. This round triples cold-address store
// traffic (tile -> d_out + two d_ws regions, runtime-guarded) to push our
// dispatch into the top-5 and read WRITE_SIZE / hbm_gbps / VALUBusy /
// OccupancyPercent / LDS conflicts directly. d_out content identical to R7.

typedef float f32x4 __attribute__((ext_vector_type(4)));

constexpr int S_LEN[31] = {
  63,62,61,60,59,58,57,56,55,54,53,52,51,50,49,
  24,23,22,21,20,19,18,17,
  8,7,6,5,4,3,2,1};
constexpr int S_ST[31] = {
  1,1,1,1,1,1,1,1,1,1,1,1,1,1,1,
  2,2,2,2,2,2,2,2,
  4,4,4,4,4,4,4,4};
constexpr int S_OFF[31] = {
  1,2,3,4,5,6,7,8,9,10,11,12,13,14,15,
  17,19,21,23,25,27,29,31,
  35,39,43,47,51,55,59,63};

// Pool chain + direct scatter into the persistent LDS tile (geometry verified
// absmax 0.0 in R4-R9). Wave-synchronous; tile is wave-private.
__device__ __forceinline__ void pool_scatter(float curx, float* tile, int lane) {
  tile[lane * 65] = curx;                   // diagonal
  float cur = curx;
#pragma unroll
  for (int m = 0; m < 31; ++m) {
    if (m == 15 || m == 23) {               // k=3, s=2
      float a = __shfl(cur, 2 * lane);
      float b = __shfl(cur, 2 * lane + 1);
      float c = __shfl(cur, 2 * lane + 2);
      cur = fmaxf(fmaxf(a, b), c);
    } else {                                // k=2, s=1
      cur = fmaxf(cur, __shfl_down(cur, 1));
    }
    if (lane < S_LEN[m]) tile[lane * (S_ST[m] * 65) + S_OFF[m]] = cur;
  }
}

__global__ void __launch_bounds__(64)
sparse_pool_probe(const float* __restrict__ x, float* __restrict__ out,
                  float* __restrict__ wsA, float* __restrict__ wsB,
                  int nrows, int ntiles) {
  __shared__ float tile[4096];              // 16 KB persistent tile
  const int lane = threadIdx.x;
  const int G = gridDim.x;

  const f32x4 z = {0.f, 0.f, 0.f, 0.f};
#pragma unroll
  for (int i = 0; i < 16; ++i)
    ((f32x4*)tile)[i * 64 + lane] = z;

  const f32x4* t4 = (const f32x4*)tile;

  int t = blockIdx.x;
  float curx = (t < nrows) ? x[(size_t)t * 64 + lane] : 1.0f;

  for (; t < ntiles; t += G) {
    pool_scatter(curx, tile, lane);

    const int tn = t + G;
    float nxx = 0.f;
    if (tn < ntiles) nxx = (tn < nrows) ? x[(size_t)tn * 64 + lane] : 1.0f;

    // Pass 1: the real output (identical to R7).
    f32x4* o4 = (f32x4*)(out + (size_t)t * 4096);
#pragma unroll
    for (int it = 0; it < 16; ++it)
      o4[it * 64 + lane] = t4[it * 64 + lane];

    // Passes 2+3: PROBE traffic to cold scratch regions (same pattern).
    f32x4* a4 = (f32x4*)(wsA + (size_t)t * 4096);
#pragma unroll
    for (int it = 0; it < 16; ++it)
      a4[it * 64 + lane] = t4[it * 64 + lane];
    f32x4* b4 = (f32x4*)(wsB + (size_t)t * 4096);
#pragma unroll
    for (int it = 0; it < 16; ++it)
      b4[it * 64 + lane] = t4[it * 64 + lane];

    curx = nxx;
  }
}

extern "C" void kernel_launch(void* const* d_in, const int* in_sizes, int n_in,
                              void* d_out, int out_size, void* d_ws, size_t ws_size,
                              hipStream_t stream) {
  const float* x = (const float*)d_in[0];        // fp32 input (32,512,64)
  float* out = (float*)d_out;                    // fp32 output

  const int nx     = in_sizes[0];                // B*D*64 = 1048576
  const int nrows  = nx / 64;                    // 16384 map tiles
  const int ntiles = out_size / 4096;            // 16448 tiles

  // Probe targets: two disjoint out-sized regions of d_ws. Runtime-guarded:
  // if ws is too small, fall back to re-writing d_out (same addresses, still
  // 3x store instructions; deterministic either way -> graph-capture safe).
  const size_t need = (size_t)ntiles * 4096;     // elements per region
  float* wsA = (ws_size >= need * 4)     ? (float*)d_ws        : out;
  float* wsB = (ws_size >= need * 8)     ? (float*)d_ws + need : out;

  const int blocks = (ntiles + 7) / 8;           // 2056 x 64 threads (R7 grid)
  sparse_pool_probe<<<dim3(blocks), 64, 0, stream>>>(x, out, wsA, wsB,
                                                     nrows, ntiles);
}

// Round 12
// 269.560 us; speedup vs baseline: 1.4005x; 1.4005x over previous
//
#include <hip/hip_runtime.h>

// SparseMaxPool — R11: revert the R10 probe; restore the best kernel (R7,
// 263.75 us). R10's probe resolved the plateau: dur_us includes ~215 us of
// harness poison fills (d_ws 1.076 GB ~170 us + d_out 269.5 MB ~45 us); the
// kernel itself runs ~45-49 us vs a 43 us write floor (269.5 MB @ 6.3 TB/s
// achievable — the fills themselves only reach 6.1-6.4 TB/s). R4/R6/R7/R9
// all sat at this floor already; the "95 us kernel" was a misattribution.
// => This structure is at the write-bandwidth roofline.
//
// Structure: one wave per tile round; persistent 16 KB LDS tile zeroed ONCE
// (valid-position set is tile-invariant, always overwritten); 31-stage pool
// chain via wave shuffles scatters straight to (i,j) LDS positions
// (conflict-free strides); emit = 16x ds_read_b128 + global dwordx4 stores;
// mask tiles = map tiles with all-ones input (maxpool(1)=1). 2056 blocks x
// 64 threads, 8 tiles each, all resident, next-x prefetched during emit.

constexpr int S_LEN[31] = {
  63,62,61,60,59,58,57,56,55,54,53,52,51,50,49,
  24,23,22,21,20,19,18,17,
  8,7,6,5,4,3,2,1};
constexpr int S_ST[31] = {
  1,1,1,1,1,1,1,1,1,1,1,1,1,1,1,
  2,2,2,2,2,2,2,2,
  4,4,4,4,4,4,4,4};
constexpr int S_OFF[31] = {
  1,2,3,4,5,6,7,8,9,10,11,12,13,14,15,
  17,19,21,23,25,27,29,31,
  35,39,43,47,51,55,59,63};

__global__ void __launch_bounds__(64)
sparse_pool_kernel(const float* __restrict__ x, float* __restrict__ out,
                   int nrows, int ntiles) {
  __shared__ float tile[4096];            // 16 KB: one 64x64 fp32 tile
  const int lane = threadIdx.x;

  // Zero the tile ONCE; the zero background persists across tiles.
  const float4 z = make_float4(0.f, 0.f, 0.f, 0.f);
#pragma unroll
  for (int i = 0; i < 16; ++i)
    ((float4*)tile)[i * 64 + lane] = z;

  int t = blockIdx.x;
  float curx = 0.f;
  if (t < ntiles) curx = (t < nrows) ? x[(size_t)t * 64 + lane] : 1.0f;

  for (; t < ntiles; t += gridDim.x) {
    // Diagonal (st=1: 2-way bank aliasing across the wave = free).
    tile[lane * 65] = curx;

    // 31-stage pool chain (verified absmax 0.0 in R4-R10), scattering each
    // stage's output straight to its tile positions: addr = lane*st*65 + off.
    float cur = curx;
#pragma unroll
    for (int m = 0; m < 31; ++m) {
      if (m == 15 || m == 23) {           // k=3, s=2
        float a = __shfl(cur, 2 * lane);
        float b = __shfl(cur, 2 * lane + 1);
        float c = __shfl(cur, 2 * lane + 2);
        cur = fmaxf(fmaxf(a, b), c);
      } else {                            // k=2, s=1
        cur = fmaxf(cur, __shfl_down(cur, 1));
      }
      if (lane < S_LEN[m]) tile[lane * (S_ST[m] * 65) + S_OFF[m]] = cur;
    }

    // Prefetch next tile's input; overlaps the emit stores below.
    const int tn = t + gridDim.x;
    float nx = 0.f;
    if (tn < ntiles) nx = (tn < nrows) ? x[(size_t)tn * 64 + lane] : 1.0f;

    // Emit: 16x (ds_read_b128 + global_store_dwordx4), fully coalesced.
    float4* o4 = (float4*)(out + (size_t)t * 4096);
    const float4* t4 = (const float4*)tile;
#pragma unroll
    for (int it = 0; it < 16; ++it)
      o4[it * 64 + lane] = t4[it * 64 + lane];

    curx = nx;
  }
}

extern "C" void kernel_launch(void* const* d_in, const int* in_sizes, int n_in,
                              void* d_out, int out_size, void* d_ws, size_t ws_size,
                              hipStream_t stream) {
  const float* x = (const float*)d_in[0];        // fp32 input (32,512,64)
  float* out = (float*)d_out;                    // fp32 output

  const int nx     = in_sizes[0];                // B*D*64 = 1048576
  const int nrows  = nx / 64;                    // 16384 map tiles
  const int ntiles = out_size / 4096;            // 16448 = map + 32 mask tiles

  // 8 tiles per block: 2056 blocks, all resident (16 KB LDS -> 10 blocks/CU
  // capacity vs 8.03 needed), single scheduling round, balanced.
  const int blocks = (ntiles + 7) / 8;
  sparse_pool_kernel<<<dim3(blocks), 64, 0, stream>>>(x, out, nrows, ntiles);
}